// Round 5
// baseline (690.598 us; speedup 1.0000x reference)
//
#include <hip/hip_runtime.h>
#include <hip/hip_bf16.h>
#include <stdint.h>

#define B_SZ 16384
#define H_SZ 1024
#define OUT_SZ 128

typedef __attribute__((ext_vector_type(4))) float f32x4;
typedef __attribute__((ext_vector_type(8))) _Float16 h16x8;
typedef unsigned short u16;
typedef unsigned int u32;

__device__ __forceinline__ u16 f2h(float f) {
  union { _Float16 h; u16 u; } v; v.h = (_Float16)f; return v.u;
}
__device__ __forceinline__ float h2f(u16 u) {
  union { u16 u; _Float16 h; } v; v.u = u; return (float)v.h;
}
__device__ __forceinline__ u32 pk2(float a, float b) {
  return (u32)f2h(a) | ((u32)f2h(b) << 16);
}

__device__ __forceinline__ void gl_lds16(const void* g, void* l) {
  __builtin_amdgcn_global_load_lds(
      (const __attribute__((address_space(1))) u32*)g,
      (__attribute__((address_space(3))) u32*)l, 16, 0, 0);
}

// ---------------------------------------------------------------------------
// 64x512 NT GEMM, K=1024: C[m,n] = sum_k A[m,k]*B[n,k], fp16 in, fp32 MFMA.
// BM=64, BN=512, BK=32, 512 threads = 8 waves (1M x 8N; per-wave 64x64 via
// 4x4 mfma 16x16x32, acc = 64 regs). Verified 2-slot double-buffer skeleton:
// stage(k+1) -> compute(k) -> __syncthreads per K-tile.
// LDS = 2 x (4K A + 32K B) = 72 KiB -> 2 independent blocks/CU; with
// launch_bounds(512,4) (<=128 regs) that's 16 waves/CU: one block's barrier
// drain is covered by the other block's compute (the R2-128^2 mechanism that
// the 1-block/CU 256^2 variants lacked). BN=512 halves A re-reads (grid.y=2).
// MODE 1: A = Z (4 stacked [B,H]; row m -> token m&3, batch m>>2);
//         epilogue: partial logits (R[t,n]+ak[n])*Zh[s,b,n] (fp16 z) ->
//         private slot ep_f[(b*16+t*4+s)*16 + yg], yg = blockIdx.y*8 + wave.
// MODE 2: v = acc + 4*ep_v[n]; fp32 -> ep_f, fp16 -> ep_b
// ---------------------------------------------------------------------------
template<int MODE>
__global__ __launch_bounds__(512, 4) void gemm_nt64(
    const u16* __restrict__ Aptr, const u16* __restrict__ Bptr,
    float* __restrict__ ep_f, u16* __restrict__ ep_b,
    const float* __restrict__ ep_v, const u16* __restrict__ Zep)
{
  constexpr int BM = 64, BN = 512, BK = 32, K = 1024;
  __shared__ __align__(16) u16 sA[2][BM * BK];
  __shared__ __align__(16) u16 sB[2][BN * BK];
  const int tid  = threadIdx.x;
  const int wave = tid >> 6;
  const int lane = tid & 63;
  const int qd   = lane >> 4;
  const int c16  = lane & 15;
  const int bm0  = blockIdx.x * BM;
  const int bn0  = blockIdx.y * BN;
  const int wn   = wave * 64;
  const size_t FBS = (size_t)B_SZ * H_SZ;

  // stage one K-tile pair into slot `buf`.
  // A: 256 x 16B chunks (rows 0..63, 4 chunks each) by threads 0..255;
  // B: 2048 chunks, 4 per thread. LDS chunk position c of row r holds
  // global chunk c ^ ((r>>1)&3) (source pre-swizzle; reads apply same XOR;
  // global_load_lds dest stays linear, <=2-way bank aliasing = free).
  auto stage = [&](int buf, int k0) {
    if (tid < 256) {
      int slot = tid;
      int r = slot >> 2, c = slot & 3;
      int cc = c ^ ((r >> 1) & 3);
      int gm = bm0 + r;
      const u16* gp;
      if (MODE == 1)
        gp = Aptr + (size_t)(gm & 3) * FBS + (size_t)(gm >> 2) * H_SZ + (k0 + cc * 8);
      else
        gp = Aptr + (size_t)gm * K + (k0 + cc * 8);
      gl_lds16(gp, &sA[buf][(size_t)(slot & ~63) * 8]);
    }
#pragma unroll
    for (int i = 0; i < 4; ++i) {
      int slot = tid + i * 512;
      int r = slot >> 2, c = slot & 3;
      int cc = c ^ ((r >> 1) & 3);
      int gn = bn0 + r;
      const u16* gp = Bptr + (size_t)gn * K + (k0 + cc * 8);
      gl_lds16(gp, &sB[buf][(size_t)(slot & ~63) * 8]);
    }
  };

  f32x4 acc[4][4];
#pragma unroll
  for (int i = 0; i < 4; ++i)
#pragma unroll
    for (int j = 0; j < 4; ++j)
      acc[i][j] = (f32x4){0.f, 0.f, 0.f, 0.f};

  stage(0, 0);
  __syncthreads();   // vmcnt(0) drain; other resident block covers the stall
  int cur = 0;
  for (int k0 = 0; k0 < K; k0 += BK) {
    if (k0 + BK < K) stage(cur ^ 1, k0 + BK);   // prefetch next K-tile
    h16x8 af[4], bfr[4];
#pragma unroll
    for (int im = 0; im < 4; ++im) {
      int m = im * 16 + c16;
      int slot = m * 4 + (qd ^ ((m >> 1) & 3));
      af[im] = *(const h16x8*)&sA[cur][slot * 8];
    }
#pragma unroll
    for (int in = 0; in < 4; ++in) {
      int n = wn + in * 16 + c16;
      int slot = n * 4 + (qd ^ ((n >> 1) & 3));
      bfr[in] = *(const h16x8*)&sB[cur][slot * 8];
    }
#pragma unroll
    for (int im = 0; im < 4; ++im)
#pragma unroll
      for (int in = 0; in < 4; ++in)
        acc[im][in] = __builtin_amdgcn_mfma_f32_16x16x32_f16(af[im], bfr[in], acc[im][in], 0, 0, 0);
    __syncthreads();
    cur ^= 1;
  }

  if constexpr (MODE == 1) {
    // acc row m = bm0+im*16+qd*4+r -> batch b = m>>2, token t = r.
    // partial logit[b,t,s] over this wave's 64 cols:
    //   sum_n (R[t,n] + ak[n]) * Zh[s][b,n]   (fp16 z, LLC-warm)
    // -> private slot ep_f[(b*16 + t*4+s)*16 + yg], yg = by*8 + wave.
    const int yg = (int)blockIdx.y * 8 + wave;
#pragma unroll
    for (int im = 0; im < 4; ++im) {
      int mrow = bm0 + im * 16 + qd * 4;
      size_t b = (size_t)(mrow >> 2);
      float p[4][4];
#pragma unroll
      for (int r = 0; r < 4; ++r)
#pragma unroll
        for (int s = 0; s < 4; ++s) p[r][s] = 0.f;
#pragma unroll
      for (int in = 0; in < 4; ++in) {
        int n = bn0 + wn + in * 16 + c16;
        float akv = ep_v[n];
        float rv[4];
#pragma unroll
        for (int r = 0; r < 4; ++r) rv[r] = acc[im][in][r] + akv;
#pragma unroll
        for (int s = 0; s < 4; ++s) {
          float zv = h2f(Zep[(size_t)s * FBS + b * H_SZ + n]);
#pragma unroll
          for (int r = 0; r < 4; ++r) p[r][s] += rv[r] * zv;
        }
      }
#pragma unroll
      for (int r = 0; r < 4; ++r)
#pragma unroll
        for (int s = 0; s < 4; ++s) {
          float v = p[r][s];
          v += __shfl_xor(v, 1);
          v += __shfl_xor(v, 2);
          v += __shfl_xor(v, 4);
          v += __shfl_xor(v, 8);
          if (c16 == 0) ep_f[(b * 16 + (size_t)(r * 4 + s)) * 16 + yg] = v;
        }
    }
  } else {   // MODE 2
#pragma unroll
    for (int im = 0; im < 4; ++im)
#pragma unroll
      for (int in = 0; in < 4; ++in) {
        int n = bn0 + wn + in * 16 + c16;
        float bvv = 4.0f * ep_v[n];
#pragma unroll
        for (int r = 0; r < 4; ++r) {
          int m = bm0 + im * 16 + qd * 4 + r;
          float v = acc[im][in][r] + bvv;
          ep_f[(size_t)m * H_SZ + n] = v;
          ep_b[(size_t)m * H_SZ + n] = f2h(v);
        }
      }
  }
}

// ---------------------------------------------------------------------------
// 128x128 NT GEMM (verified 2-phase) — kept for the small shapes:
// MODE 0: store fp16 C -> ep_b (AT prep, 1024^3)
// MODE 3: ep_f[m*N+n] = acc + ep_v[n]  (fc logits, N=128)
// ---------------------------------------------------------------------------
template<int MODE>
__global__ __launch_bounds__(256, 4) void gemm_nt(
    const u16* __restrict__ Aptr, const u16* __restrict__ Bptr,
    int N, int K,
    float* __restrict__ ep_f, u16* __restrict__ ep_b,
    const float* __restrict__ ep_v)
{
  constexpr int BM = 128, BN = 128, BK = 32;
  __shared__ __align__(16) u16 sA[2][BM * BK];
  __shared__ __align__(16) u16 sB[2][BN * BK];
  const int tid  = threadIdx.x;
  const int wave = tid >> 6;
  const int lane = tid & 63;
  const int qd   = lane >> 4;
  const int c16  = lane & 15;
  const int bm0  = blockIdx.x * BM;
  const int bn0  = blockIdx.y * BN;
  const int wm   = (wave >> 1) * 64;
  const int wn   = (wave & 1) * 64;

  auto stage = [&](int buf, int k0) {
#pragma unroll
    for (int i = 0; i < 2; ++i) {
      int slot = tid + i * 256;
      int r = slot >> 2, pp = slot & 3;
      int cc = pp ^ ((r >> 1) & 3);
      {
        int gm = bm0 + r;
        const u16* gp = Aptr + (size_t)gm * K + (k0 + cc * 8);
        gl_lds16(gp, &sA[buf][(size_t)(slot & ~63) * 8]);
      }
      {
        int gn = bn0 + r;
        const u16* gp = Bptr + (size_t)gn * K + (k0 + cc * 8);
        gl_lds16(gp, &sB[buf][(size_t)(slot & ~63) * 8]);
      }
    }
  };

  f32x4 acc[4][4];
#pragma unroll
  for (int i = 0; i < 4; ++i)
#pragma unroll
    for (int j = 0; j < 4; ++j)
      acc[i][j] = (f32x4){0.f, 0.f, 0.f, 0.f};

  stage(0, 0);
  __syncthreads();
  int cur = 0;
  for (int k0 = 0; k0 < K; k0 += BK) {
    if (k0 + BK < K) stage(cur ^ 1, k0 + BK);
    h16x8 af[4], bfr[4];
#pragma unroll
    for (int im = 0; im < 4; ++im) {
      int m = wm + im * 16 + c16;
      int slot = m * 4 + (qd ^ ((m >> 1) & 3));
      af[im] = *(const h16x8*)&sA[cur][slot * 8];
    }
#pragma unroll
    for (int in = 0; in < 4; ++in) {
      int n = wn + in * 16 + c16;
      int slot = n * 4 + (qd ^ ((n >> 1) & 3));
      bfr[in] = *(const h16x8*)&sB[cur][slot * 8];
    }
#pragma unroll
    for (int im = 0; im < 4; ++im)
#pragma unroll
      for (int in = 0; in < 4; ++in)
        acc[im][in] = __builtin_amdgcn_mfma_f32_16x16x32_f16(af[im], bfr[in], acc[im][in], 0, 0, 0);
    __syncthreads();
    cur ^= 1;
  }

  if constexpr (MODE == 0) {
#pragma unroll
    for (int im = 0; im < 4; ++im)
#pragma unroll
      for (int in = 0; in < 4; ++in) {
        int n = bn0 + wn + in * 16 + c16;
#pragma unroll
        for (int r = 0; r < 4; ++r) {
          int m = bm0 + wm + im * 16 + qd * 4 + r;
          ep_b[(size_t)m * N + n] = f2h(acc[im][in][r]);
        }
      }
  } else {
#pragma unroll
    for (int im = 0; im < 4; ++im)
#pragma unroll
      for (int in = 0; in < 4; ++in) {
        int n = bn0 + wn + in * 16 + c16;
        float bc = ep_v[n];
#pragma unroll
        for (int r = 0; r < 4; ++r) {
          int m = bm0 + wm + im * 16 + qd * 4 + r;
          ep_f[(size_t)m * N + n] = acc[im][in][r] + bc;
        }
      }
  }
}

// ---------------------------------------------------------------------------
// prep_weights: [0,1024) Wq->fp16; [1024,2048) Wk->fp16;
// [2048,3072) WvT fp16 transpose; [3072,3200) WfcT fp16 transpose;
// [3200,3456) ak[h] = sum_i Wk[h,i]*bq[i]  (fp32)
// ---------------------------------------------------------------------------
__global__ __launch_bounds__(256) void prep_weights(
    const float* __restrict__ Wq, const float* __restrict__ Wk,
    const float* __restrict__ Wv, const float* __restrict__ Wfc,
    const float* __restrict__ bq,
    u16* __restrict__ Wq16, u16* __restrict__ Wk16,
    u16* __restrict__ WvT, u16* __restrict__ WfcT,
    float* __restrict__ ak)
{
  __shared__ float t[32][33];
  int blk = blockIdx.x, tid = threadIdx.x;
  if (blk < 2048) {
    const float* src = (blk < 1024) ? Wq : Wk;
    u16* dst = (blk < 1024) ? Wq16 : Wk16;
    size_t i0 = (size_t)(blk & 1023) * 1024 + tid * 4;
    float4 v = *(const float4*)(src + i0);
    *(uint2*)(dst + i0) = make_uint2(pk2(v.x, v.y), pk2(v.z, v.w));
  } else if (blk < 3200) {
    int lx = tid & 31, ly = tid >> 5;
    if (blk < 3072) {
      int ti = blk - 2048;
      int tx = ti & 31, ty = ti >> 5;
#pragma unroll
      for (int k = 0; k < 4; ++k)
        t[ly + 8 * k][lx] = Wv[(size_t)(ty * 32 + ly + 8 * k) * 1024 + tx * 32 + lx];
      __syncthreads();
#pragma unroll
      for (int k = 0; k < 4; ++k)
        WvT[(size_t)(tx * 32 + ly + 8 * k) * 1024 + ty * 32 + lx] = f2h(t[lx][ly + 8 * k]);
    } else {
      int ti = blk - 3072;
      int tx = ti & 3, ty = ti >> 2;
#pragma unroll
      for (int k = 0; k < 4; ++k)
        t[ly + 8 * k][lx] = Wfc[(size_t)(ty * 32 + ly + 8 * k) * 128 + tx * 32 + lx];
      __syncthreads();
#pragma unroll
      for (int k = 0; k < 4; ++k)
        WfcT[(size_t)(tx * 32 + ly + 8 * k) * 1024 + ty * 32 + lx] = f2h(t[lx][ly + 8 * k]);
    }
  } else {
    int wave = tid >> 6, lane = tid & 63;
    int row = (blk - 3200) * 4 + wave;
    float s = 0.f;
    for (int i = lane; i < 1024; i += 64)
      s += Wk[(size_t)row * 1024 + i] * bq[i];
#pragma unroll
    for (int m = 1; m < 64; m <<= 1) s += __shfl_xor(s, m);
    if (lane == 0) ak[row] = s;
  }
}

__global__ __launch_bounds__(256) void convert4(
    const float* __restrict__ f1, const float* __restrict__ f2,
    const float* __restrict__ f3, const float* __restrict__ f4,
    u16* __restrict__ Zh)
{
  int a = blockIdx.x >> 13;
  const float* f = (a == 0) ? f1 : (a == 1) ? f2 : (a == 2) ? f3 : f4;
  size_t off = (size_t)(blockIdx.x & 8191) * 2048 + threadIdx.x * 8;
  float4 v0 = *(const float4*)(f + off);
  float4 v1 = *(const float4*)(f + off + 4);
  *(uint4*)(Zh + (size_t)a * B_SZ * H_SZ + off) =
      make_uint4(pk2(v0.x, v0.y), pk2(v0.z, v0.w), pk2(v1.x, v1.y), pk2(v1.z, v1.w));
}

// one wave per batch: sum the 16 per-slot partial logits -> 4x4 logits,
// softmax rows, col-sums w_s, g = sum_s w_s z_s
__global__ __launch_bounds__(256) void softmax_g(
    const float* __restrict__ pl, const u16* __restrict__ Zh,
    u16* __restrict__ G)
{
  const size_t FBS = (size_t)B_SZ * H_SZ;
  int wave = threadIdx.x >> 6, lane = threadIdx.x & 63;
  size_t b = (size_t)blockIdx.x * 4 + wave;
  // pl[b][rs][yg16]: lane reads 4 of the 16 slots for rs = lane>>2
  float4 pv = *(const float4*)(pl + b * 256 + (size_t)lane * 4);
  float part = pv.x + pv.y + pv.z + pv.w;
  part += __shfl_xor(part, 1);
  part += __shfl_xor(part, 2);
  // lane group (lane>>2) now holds logit[rs]; broadcast all 16 to every lane
  float l[16];
#pragma unroll
  for (int i = 0; i < 16; ++i) l[i] = __shfl(part, i * 4);
  float w0 = 0, w1 = 0, w2 = 0, w3 = 0;
#pragma unroll
  for (int t = 0; t < 4; ++t) {
    float a0 = l[t * 4], a1 = l[t * 4 + 1], a2 = l[t * 4 + 2], a3 = l[t * 4 + 3];
    float mx = fmaxf(fmaxf(a0, a1), fmaxf(a2, a3));
    float e0 = __expf(a0 - mx), e1 = __expf(a1 - mx), e2 = __expf(a2 - mx), e3 = __expf(a3 - mx);
    float inv = 1.0f / (e0 + e1 + e2 + e3);
    w0 += e0 * inv; w1 += e1 * inv; w2 += e2 * inv; w3 += e3 * inv;
  }
#pragma unroll
  for (int ch = 0; ch < 2; ++ch) {
    size_t h0 = (size_t)lane * 8 + ch * 512;
    float g[8];
#pragma unroll
    for (int j = 0; j < 8; ++j) g[j] = 0.f;
#pragma unroll
    for (int s = 0; s < 4; ++s) {
      float ws = (s == 0) ? w0 : (s == 1) ? w1 : (s == 2) ? w2 : w3;
      uint4 zz = *(const uint4*)(Zh + (size_t)s * FBS + b * H_SZ + h0);
      u32 zs[4] = {zz.x, zz.y, zz.z, zz.w};
#pragma unroll
      for (int j = 0; j < 4; ++j) {
        g[2 * j]     += ws * h2f((u16)(zs[j] & 0xffffu));
        g[2 * j + 1] += ws * h2f((u16)(zs[j] >> 16));
      }
    }
    *(uint4*)(G + b * H_SZ + h0) =
        make_uint4(pk2(g[0], g[1]), pk2(g[2], g[3]), pk2(g[4], g[5]), pk2(g[6], g[7]));
  }
}

// one wave per row: softmax over 128 fc logits
__global__ __launch_bounds__(256) void softmax_out(
    const float* __restrict__ L2, float* __restrict__ out)
{
  int wave = threadIdx.x >> 6, lane = threadIdx.x & 63;
  size_t row = (size_t)blockIdx.x * 4 + wave;
  float2 v = *(const float2*)(L2 + row * 128 + lane * 2);
  float mx = fmaxf(v.x, v.y);
#pragma unroll
  for (int m = 1; m < 64; m <<= 1) mx = fmaxf(mx, __shfl_xor(mx, m));
  float e0 = __expf(v.x - mx), e1 = __expf(v.y - mx);
  float s = e0 + e1;
#pragma unroll
  for (int m = 1; m < 64; m <<= 1) s += __shfl_xor(s, m);
  float inv = 1.0f / s;
  *(float2*)(out + row * 128 + lane * 2) = make_float2(e0 * inv, e1 * inv);
}

extern "C" void kernel_launch(void* const* d_in, const int* in_sizes, int n_in,
                              void* d_out, int out_size, void* d_ws, size_t ws_size,
                              hipStream_t stream)
{
  const float* f1  = (const float*)d_in[0];
  const float* f2  = (const float*)d_in[1];
  const float* f3  = (const float*)d_in[2];
  const float* f4  = (const float*)d_in[3];
  const float* Wq  = (const float*)d_in[4];
  const float* bq  = (const float*)d_in[5];
  const float* Wk  = (const float*)d_in[6];
  // d_in[7] = bk: logit contribution constant over softmax axis -> dropped.
  const float* Wv  = (const float*)d_in[8];
  const float* bv  = (const float*)d_in[9];
  const float* Wfc = (const float*)d_in[10];
  const float* bfc = (const float*)d_in[11];

  float* x_out = (float*)d_out;
  float* out2  = x_out + (size_t)B_SZ * H_SZ;

  const size_t BH = (size_t)B_SZ * H_SZ;
  const size_t HH = (size_t)H_SZ * H_SZ;
  char* w = (char*)d_ws;
  u16* Zh   = (u16*)w;  w += 4 * BH * sizeof(u16);   // 128 MiB fp16 z
  u16* G    = (u16*)w;  w += BH * sizeof(u16);       // 32 MiB
  u16* Xh   = (u16*)w;  w += BH * sizeof(u16);       // 32 MiB
  u16* Wq16 = (u16*)w;  w += HH * 2;
  u16* Wk16 = (u16*)w;  w += HH * 2;
  u16* AT   = (u16*)w;  w += HH * 2;   // AT[i,h] = sum_j Wk[i,j]Wq[h,j]
  u16* WvT  = (u16*)w;  w += HH * 2;   // WvT[n,k] = Wv[k,n]
  u16* WfcT = (u16*)w;  w += (size_t)OUT_SZ * H_SZ * 2;
  float* ak  = (float*)w;  w += H_SZ * sizeof(float);
  float* fcl = (float*)w;  w += (size_t)B_SZ * OUT_SZ * sizeof(float);
  // pl (16 MiB partial logits) overlays the start of Xh: pl is produced by
  // gemm_nt64<1> and fully consumed by softmax_g BEFORE gemm_nt64<2>
  // writes Xh. Keeps total workspace within the previously-passing layout.
  float* pl  = (float*)Xh;

  prep_weights<<<3456, 256, 0, stream>>>(Wq, Wk, Wv, Wfc, bq,
      Wq16, Wk16, WvT, WfcT, ak);
  convert4<<<32768, 256, 0, stream>>>(f1, f2, f3, f4, Zh);
  // AT = Wk @ Wq^T (fp16 out)
  gemm_nt<0><<<dim3(8, 8), 256, 0, stream>>>(
      Wk16, Wq16, 1024, 1024, nullptr, AT, nullptr);
  // R = Z @ AT^T, fused (R+ak)·z epilogue -> partial logits pl[b][ts][yg]
  gemm_nt64<1><<<dim3(1024, 2), 512, 0, stream>>>(
      Zh, AT, pl, nullptr, ak, Zh);
  softmax_g<<<4096, 256, 0, stream>>>(pl, Zh, G);
  // x = G @ Wv + 4*bv  (fp32 -> d_out, fp16 -> Xh)
  gemm_nt64<2><<<dim3(256, 2), 512, 0, stream>>>(
      G, WvT, x_out, Xh, bv, nullptr);
  // fc logits = x @ Wfc + bfc
  gemm_nt<3><<<dim3(128, 1), 256, 0, stream>>>(
      Xh, WfcT, 128, 1024, fcl, nullptr, bfc);
  softmax_out<<<4096, 256, 0, stream>>>(fcl, out2);
}